// Round 2
// baseline (203.961 us; speedup 1.0000x reference)
//
#include <hip/hip_runtime.h>

// AllInOneFlow: y = perm-scatter( scale * concat(x1, x2*exp(ls)+off) + goff ), log_jac
//   x1,x2 = inverse-perm split of x; MLP 32->256->256->64 (gelu,gelu,linear)
// B=131072, D=64, H=256. GEMMs via bf16-split (hi+lo, 3 products) MFMA 16x16x32.
// h stored in LDS as packed u32 (bf16 hi | lo<<16), split ONCE at write time.

#define NB  131072
#define DD  64
#define DD1 32
#define HH  256

typedef float f32x4 __attribute__((ext_vector_type(4)));
typedef short bf16x8 __attribute__((ext_vector_type(8)));
typedef unsigned int u32;
typedef u32 u32x4 __attribute__((ext_vector_type(4)));

// Pre-split, pre-transposed weights in device globals (rewritten fully every launch
// by flow_prep, so no cross-call state dependence).
__device__ __align__(16) unsigned short g_w1h[DD1 * HH], g_w1l[DD1 * HH]; // [n][k] n<256,k<32
__device__ __align__(16) unsigned short g_w2h[HH * HH],  g_w2l[HH * HH];  // [n][k] 256x256
__device__ __align__(16) unsigned short g_w3h[DD * HH],  g_w3l[DD * HH];  // [n][k] n<64,k<256
__device__ int   g_invp[64];
__device__ float g_egls[64];
__device__ float g_sgls;

__device__ __forceinline__ unsigned short f2bf(float x) {
  unsigned int u = __float_as_uint(x);
  unsigned int r = u + 0x7FFFu + ((u >> 16) & 1u); // RNE to bf16
  return (unsigned short)(r >> 16);
}
__device__ __forceinline__ float bf2f(unsigned short b) {
  return __uint_as_float(((unsigned int)b) << 16);
}
__device__ __forceinline__ float fast_tanh(float z) {
  // 1 - 2/(1+e^{2z}); stable for all z (+inf -> 1, -inf -> -1)
  float e = __expf(2.0f * z);
  return 1.0f - 2.0f * __builtin_amdgcn_rcpf(e + 1.0f);
}
__device__ __forceinline__ float gelu_tanh(float x) {
  // jax.nn.gelu approximate=True: 0.5x(1+tanh(0.79788456(x+0.044715x^3)))
  float u = x * x;
  float inner = x * (0.7978845608028654f + 0.03567740814183556f * u);
  return 0.5f * x * (1.0f + fast_tanh(inner));
}
__device__ __forceinline__ void split8(const float* v, bf16x8& hi, bf16x8& lo) {
#pragma unroll
  for (int j = 0; j < 8; ++j) {
    unsigned short h = f2bf(v[j]);
    hi[j] = (short)h;
    lo[j] = (short)f2bf(v[j] - bf2f(h));
  }
}
__device__ __forceinline__ u32 pack_h(float hv) {
  unsigned short h = f2bf(hv);
  unsigned short l = f2bf(hv - bf2f(h));
  return (u32)h | ((u32)l << 16);
}

#define MFMA(a, b, c) __builtin_amdgcn_mfma_f32_16x16x32_bf16((a), (b), (c), 0, 0, 0)
// XOR-swizzled word index for the packed-h LDS tile [64 rows][256 cols].
// Applied identically on write and read; preserves 4-word (16B) chunks.
#define SWZ(row, col) (((row) << 8) + ((col) ^ (((row) & 7) << 2)))

// ---------------- prep: transpose + bf16-split weights, invp, gls ----------------
__global__ void flow_prep(const float* __restrict__ W1, const float* __restrict__ W2,
                          const float* __restrict__ W3, const int* __restrict__ perm,
                          const float* __restrict__ gin) {
  int idx = blockIdx.x * blockDim.x + threadIdx.x;
  int stride = gridDim.x * blockDim.x;
  for (int i = idx; i < HH * HH; i += stride) { // w2t[n][k] = W2[k][n]
    int n = i >> 8, k = i & 255;
    float v = W2[k * HH + n];
    unsigned short h = f2bf(v);
    g_w2h[i] = h; g_w2l[i] = f2bf(v - bf2f(h));
  }
  for (int i = idx; i < DD1 * HH; i += stride) { // w1t[n][k] = W1[k][n], k<32
    int n = i >> 5, k = i & 31;
    float v = W1[k * HH + n];
    unsigned short h = f2bf(v);
    g_w1h[i] = h; g_w1l[i] = f2bf(v - bf2f(h));
  }
  for (int i = idx; i < DD * HH; i += stride) { // w3t[n][k] = W3[k][n], n<64
    int n = i >> 8, k = i & 255;
    float v = W3[k * DD + n];
    unsigned short h = f2bf(v);
    g_w3h[i] = h; g_w3l[i] = f2bf(v - bf2f(h));
  }
  if (blockIdx.x == 0 && threadIdx.x < 64) {
    int t = threadIdx.x;
    g_invp[perm[t]] = t; // inv_perm = argsort(perm)
    float gl = 4.0f * tanhf(gin[t] * 0.25f);
    g_egls[t] = expf(gl);
    float s = gl;
#pragma unroll
    for (int m = 1; m < 64; m <<= 1) s += __shfl_xor(s, m);
    if (t == 0) g_sgls = s;
  }
}

// ---------------- main: 64 rows/block, 4 waves; waves split N dim ----------------
// LDS (64 KiB u32[64*256]), time-multiplexed:
//   x-stage   : f32, stride 68 (17.4 KB)   -- dead after Phase B
//   h packed  : u32, SWZ layout (64 KB)    -- GEMM1 out / GEMM2 in-out / GEMM3 in
//   params/y  : f32, stride 68 (17.4 KB)   -- after last h read
__global__ __launch_bounds__(256, 2) void flow_main(
    const float* __restrict__ x, const int* __restrict__ perm,
    const float* __restrict__ b1, const float* __restrict__ b2,
    const float* __restrict__ b3, const float* __restrict__ goff,
    float* __restrict__ out) {
  __shared__ u32 lds[64 * 256]; // exactly 64 KiB -> 2 blocks/CU
  float* ldsf = (float*)lds;
  const int tid = threadIdx.x;
  const int wave = tid >> 6, lane = tid & 63;
  const int g = lane >> 4, lm = lane & 15;
  const size_t row0 = (size_t)blockIdx.x * 64;

  // Phase A: stage x tile (64x64 f32) into LDS, stride 68
  {
    const float4* xv = (const float4*)(x + row0 * DD);
#pragma unroll
    for (int t = 0; t < 4; ++t) {
      int i = tid + t * 256;
      int r = i >> 4, c4 = i & 15;
      float4 v = xv[i];
      *(float4*)(ldsf + r * 68 + c4 * 4) = v;
    }
  }
  __syncthreads();

  // Phase B: gather x1 A-fragments (inverse-perm) + keep x1/x2 for this wave's
  // 16 epilogue rows in C/D layout (row=(l>>4)*4+r, col=lm).
  int ic[8];
#pragma unroll
  for (int j = 0; j < 8; ++j) ic[j] = g_invp[g * 8 + j];
  bf16x8 a1h[4], a1l[4];
#pragma unroll
  for (int rt = 0; rt < 4; ++rt) {
    float v[8];
#pragma unroll
    for (int j = 0; j < 8; ++j) v[j] = ldsf[(rt * 16 + lm) * 68 + ic[j]];
    split8(v, a1h[rt], a1l[rt]);
  }
  float x1cd[8], x2cd[8];
  {
    int c1[2], c2[2];
#pragma unroll
    for (int ct = 0; ct < 2; ++ct) {
      c1[ct] = g_invp[ct * 16 + lm];
      c2[ct] = g_invp[32 + ct * 16 + lm];
    }
#pragma unroll
    for (int ct = 0; ct < 2; ++ct)
#pragma unroll
      for (int r = 0; r < 4; ++r) {
        int row = wave * 16 + g * 4 + r;
        x1cd[ct * 4 + r] = ldsf[row * 68 + c1[ct]];
        x2cd[ct * 4 + r] = ldsf[row * 68 + c2[ct]];
      }
  }
  __syncthreads(); // x-stage dead; region becomes packed h

  // Phase C: GEMM1 (K=32): wave owns cols [wave*64, wave*64+64), all 64 rows
  {
    f32x4 acc[4][4]; // [cti][rt]
#pragma unroll
    for (int cti = 0; cti < 4; ++cti) {
      float bb = b1[(wave * 4 + cti) * 16 + lm];
#pragma unroll
      for (int rt = 0; rt < 4; ++rt) acc[cti][rt] = f32x4{bb, bb, bb, bb};
    }
#pragma unroll
    for (int cti = 0; cti < 4; ++cti) {
      int col = (wave * 4 + cti) * 16 + lm;
      bf16x8 bh = *(const bf16x8*)(g_w1h + col * 32 + g * 8);
      bf16x8 bl = *(const bf16x8*)(g_w1l + col * 32 + g * 8);
#pragma unroll
      for (int rt = 0; rt < 4; ++rt) {
        acc[cti][rt] = MFMA(a1h[rt], bh, acc[cti][rt]);
        acc[cti][rt] = MFMA(a1h[rt], bl, acc[cti][rt]);
        acc[cti][rt] = MFMA(a1l[rt], bh, acc[cti][rt]);
      }
    }
    // gelu + split-once + packed store
#pragma unroll
    for (int cti = 0; cti < 4; ++cti) {
      int col = (wave * 4 + cti) * 16 + lm;
#pragma unroll
      for (int rt = 0; rt < 4; ++rt)
#pragma unroll
        for (int r = 0; r < 4; ++r) {
          int row = rt * 16 + g * 4 + r;
          lds[SWZ(row, col)] = pack_h(gelu_tanh(acc[cti][rt][r]));
        }
    }
  }
  __syncthreads();

  // Phase D: GEMM2 (K=256); A-fragments unpacked from packed h (no split here)
  f32x4 acc2[4][4];
#pragma unroll
  for (int cti = 0; cti < 4; ++cti) {
    float bb = b2[(wave * 4 + cti) * 16 + lm];
#pragma unroll
    for (int rt = 0; rt < 4; ++rt) acc2[cti][rt] = f32x4{bb, bb, bb, bb};
  }
#pragma unroll 2
  for (int kk = 0; kk < 8; ++kk) {
    bf16x8 ah[4], al[4];
#pragma unroll
    for (int rt = 0; rt < 4; ++rt) {
      int row = rt * 16 + lm;
      int c0 = kk * 32 + g * 8;
      u32x4 q0 = *(const u32x4*)(lds + SWZ(row, c0));
      u32x4 q1 = *(const u32x4*)(lds + SWZ(row, c0 + 4));
#pragma unroll
      for (int j = 0; j < 4; ++j) {
        ah[rt][j]     = (short)(q0[j] & 0xffffu);
        al[rt][j]     = (short)(q0[j] >> 16);
        ah[rt][4 + j] = (short)(q1[j] & 0xffffu);
        al[rt][4 + j] = (short)(q1[j] >> 16);
      }
    }
#pragma unroll
    for (int cti = 0; cti < 4; ++cti) {
      int off = ((wave * 4 + cti) * 16 + lm) * 256 + kk * 32 + g * 8;
      bf16x8 bh = *(const bf16x8*)(g_w2h + off);
      bf16x8 bl = *(const bf16x8*)(g_w2l + off);
#pragma unroll
      for (int rt = 0; rt < 4; ++rt) {
        acc2[cti][rt] = MFMA(ah[rt], bh, acc2[cti][rt]);
        acc2[cti][rt] = MFMA(ah[rt], bl, acc2[cti][rt]);
        acc2[cti][rt] = MFMA(al[rt], bh, acc2[cti][rt]);
      }
    }
  }
  __syncthreads(); // all h1 reads done before overwrite
#pragma unroll
  for (int cti = 0; cti < 4; ++cti) {
    int col = (wave * 4 + cti) * 16 + lm;
#pragma unroll
    for (int rt = 0; rt < 4; ++rt)
#pragma unroll
      for (int r = 0; r < 4; ++r) {
        int row = rt * 16 + g * 4 + r;
        lds[SWZ(row, col)] = pack_h(gelu_tanh(acc2[cti][rt][r]));
      }
  }
  __syncthreads();

  // Phase F: GEMM3 (K=256, N=64): wave owns cols [wave*16, wave*16+16)
  f32x4 acc3[4];
  {
    float bb = b3[wave * 16 + lm];
#pragma unroll
    for (int rt = 0; rt < 4; ++rt) acc3[rt] = f32x4{bb, bb, bb, bb};
  }
#pragma unroll 2
  for (int kk = 0; kk < 8; ++kk) {
    bf16x8 ah[4], al[4];
#pragma unroll
    for (int rt = 0; rt < 4; ++rt) {
      int row = rt * 16 + lm;
      int c0 = kk * 32 + g * 8;
      u32x4 q0 = *(const u32x4*)(lds + SWZ(row, c0));
      u32x4 q1 = *(const u32x4*)(lds + SWZ(row, c0 + 4));
#pragma unroll
      for (int j = 0; j < 4; ++j) {
        ah[rt][j]     = (short)(q0[j] & 0xffffu);
        al[rt][j]     = (short)(q0[j] >> 16);
        ah[rt][4 + j] = (short)(q1[j] & 0xffffu);
        al[rt][4 + j] = (short)(q1[j] >> 16);
      }
    }
    int off = (wave * 16 + lm) * 256 + kk * 32 + g * 8;
    bf16x8 bh = *(const bf16x8*)(g_w3h + off);
    bf16x8 bl = *(const bf16x8*)(g_w3l + off);
#pragma unroll
    for (int rt = 0; rt < 4; ++rt) {
      acc3[rt] = MFMA(ah[rt], bh, acc3[rt]);
      acc3[rt] = MFMA(ah[rt], bl, acc3[rt]);
      acc3[rt] = MFMA(al[rt], bh, acc3[rt]);
    }
  }
  __syncthreads(); // all h2 reads done
  // params -> LDS f32 (stride 68), col = wave*16+lm, all 64 rows
#pragma unroll
  for (int rt = 0; rt < 4; ++rt)
#pragma unroll
    for (int r = 0; r < 4; ++r)
      ldsf[(rt * 16 + g * 4 + r) * 68 + wave * 16 + lm] = acc3[rt][r];
  __syncthreads();

  // Phase G: epilogue on this wave's 16 rows. Reads of params precede writes of
  // y in program order; rows are wave-private; LDS ops complete in order per wave.
  float pls[8], pof[8];
#pragma unroll
  for (int ct = 0; ct < 2; ++ct)
#pragma unroll
    for (int r = 0; r < 4; ++r) {
      int row = wave * 16 + g * 4 + r;
      pls[ct * 4 + r] = ldsf[row * 68 + ct * 16 + lm];      // log-scale raw
      pof[ct * 4 + r] = ldsf[row * 68 + 32 + ct * 16 + lm]; // offset
    }
  float sg = g_sgls;
  float lj[4] = {0.f, 0.f, 0.f, 0.f};
#pragma unroll
  for (int ct = 0; ct < 2; ++ct) {
    int c1 = ct * 16 + lm, c2v = 32 + ct * 16 + lm;
    float e1 = g_egls[c1], o1 = goff[c1];
    float e2 = g_egls[c2v], o2 = goff[c2v];
#pragma unroll
    for (int r = 0; r < 4; ++r) {
      int row = wave * 16 + g * 4 + r;
      float ls = 2.0f * fast_tanh(0.1f * pls[ct * 4 + r]);
      lj[r] += ls;
      float y2 = x2cd[ct * 4 + r] * __expf(ls) + pof[ct * 4 + r];
      ldsf[row * 68 + c1]  = x1cd[ct * 4 + r] * e1 + o1;
      ldsf[row * 68 + c2v] = y2 * e2 + o2;
    }
  }
#pragma unroll
  for (int r = 0; r < 4; ++r) {
    float v = lj[r];
    v += __shfl_xor(v, 1); v += __shfl_xor(v, 2);
    v += __shfl_xor(v, 4); v += __shfl_xor(v, 8);
    if (lm == 0) {
      size_t row = row0 + wave * 16 + g * 4 + r;
      out[(size_t)NB * DD + row] = v + sg;
    }
  }
  int pj = perm[lane];
#pragma unroll
  for (int rl = 0; rl < 16; ++rl) {
    size_t row = row0 + wave * 16 + rl;
    out[row * DD + lane] = ldsf[(wave * 16 + rl) * 68 + pj];
  }
}

extern "C" void kernel_launch(void* const* d_in, const int* in_sizes, int n_in,
                              void* d_out, int out_size, void* d_ws, size_t ws_size,
                              hipStream_t stream) {
  const float* x    = (const float*)d_in[0];
  const int*   perm = (const int*)d_in[1];
  const float* W1   = (const float*)d_in[2];
  const float* b1   = (const float*)d_in[3];
  const float* W2   = (const float*)d_in[4];
  const float* b2   = (const float*)d_in[5];
  const float* W3   = (const float*)d_in[6];
  const float* b3   = (const float*)d_in[7];
  const float* gls  = (const float*)d_in[8];
  const float* goff = (const float*)d_in[9];
  (void)in_sizes; (void)n_in; (void)d_ws; (void)ws_size; (void)out_size;

  flow_prep<<<256, 256, 0, stream>>>(W1, W2, W3, perm, gls);
  flow_main<<<NB / 64, 256, 0, stream>>>(x, perm, b1, b2, b3, goff, (float*)d_out);
}